// Round 2
// 1098.532 us; speedup vs baseline: 2.3187x; 2.3187x over previous
//
#include <hip/hip_runtime.h>
#include <hip/hip_bf16.h>

#define ALPHA 0.2f

typedef unsigned short u16;
typedef __attribute__((ext_vector_type(8))) short bf16x8_t;   // MFMA A/B frag (8 bf16)
typedef __attribute__((ext_vector_type(4))) float f32x4_t;    // MFMA C/D frag
typedef __attribute__((ext_vector_type(4))) unsigned short u16x4;
typedef __attribute__((ext_vector_type(8))) unsigned short u16x8;

__device__ __forceinline__ u16 f2bf_rne(float f) {
  unsigned u = __float_as_uint(f);
  u += 0x7fffu + ((u >> 16) & 1u);        // round-to-nearest-even
  return (u16)(u >> 16);
}

// convert 8 consecutive fp32 -> bf16x8 MFMA fragment (global read)
__device__ __forceinline__ bf16x8_t cvt8(const float* __restrict__ p) {
  float4 u0 = *(const float4*)p;
  float4 u1 = *(const float4*)(p + 4);
  union { bf16x8_t v; __hip_bfloat162 h[4]; } cv;
  cv.h[0] = __float22bfloat162_rn(make_float2(u0.x, u0.y));
  cv.h[1] = __float22bfloat162_rn(make_float2(u0.z, u0.w));
  cv.h[2] = __float22bfloat162_rn(make_float2(u1.x, u1.y));
  cv.h[3] = __float22bfloat162_rn(make_float2(u1.z, u1.w));
  return cv.v;
}

// pack 8 fp32 (two float4 already in regs) -> 8 bf16
__device__ __forceinline__ u16x8 cvt8pk(float4 a, float4 b) {
  union { u16x8 v; __hip_bfloat162 h[4]; } cv;
  cv.h[0] = __float22bfloat162_rn(make_float2(a.x, a.y));
  cv.h[1] = __float22bfloat162_rn(make_float2(a.z, a.w));
  cv.h[2] = __float22bfloat162_rn(make_float2(b.x, b.y));
  cv.h[3] = __float22bfloat162_rn(make_float2(b.z, b.w));
  return cv.v;
}

__device__ __forceinline__ float lrelu(float v) { return v > 0.f ? v : ALPHA * v; }

// ---------------- K0: convert fc_w / q_w / k_w / v_w to bf16 into ws ----------
__global__ __launch_bounds__(256) void convert_weights(
    const float* __restrict__ fcw, const float* __restrict__ qw,
    const float* __restrict__ kw, const float* __restrict__ vw,
    u16* __restrict__ dst) {
  int arr = blockIdx.x >> 8;                                   // 0..3
  int i = (((blockIdx.x & 255) << 8) + threadIdx.x) << 2;      // elem idx, x4
  const float* src = (arr == 0) ? fcw : (arr == 1) ? qw : (arr == 2) ? kw : vw;
  float4 v = *(const float4*)(src + i);
  u16x4 r;
  r.x = f2bf_rne(v.x); r.y = f2bf_rne(v.y); r.z = f2bf_rne(v.z); r.w = f2bf_rne(v.w);
  *(u16x4*)(dst + (size_t)arr * 262144 + i) = r;
}

#define XH_STRIDE 520

// ---------------- K1: xh = lrelu(x@fc_w^T + fc_b); query = xh@q_w^T + q_b ------
// 128 blocks x 512 threads; block owns 16 batches (was 16 blocks -> 6% of GPU).
__global__ __launch_bounds__(512) void xh_query(
    const float* __restrict__ x, const u16* __restrict__ fcw_bf,
    const u16* __restrict__ qw_bf, const float* __restrict__ fcb,
    const float* __restrict__ qb, float* __restrict__ xh_ws,
    float* __restrict__ q_ws) {
  __shared__ u16 xh[16 * XH_STRIDE];   // 16.6 KB
  const int tid = threadIdx.x;
  const int w = tid >> 6;
  const int lane = tid & 63;
  const int lc = lane & 15;
  const int lq = lane >> 4;
  const int colBase = w << 6;
  const int kko = lq << 3;
  const size_t b0 = (size_t)blockIdx.x * 16;
  const f32x4_t fzero = {0.f, 0.f, 0.f, 0.f};

  // ---- phase A (operand-swapped: A=fc_w rows h, B=x rows l) -> xh[l][h] ----
  {
    f32x4_t acc[4] = {fzero, fzero, fzero, fzero};
    const float* xb = x + b0 * 512;
    for (int k0 = 0; k0 < 512; k0 += 32) {
      const int kk = k0 + kko;
      bf16x8_t bv = cvt8(xb + lc * 512 + kk);
#pragma unroll
      for (int mt = 0; mt < 4; mt++) {
        bf16x8_t af = *(const bf16x8_t*)(fcw_bf + (colBase + mt * 16 + lc) * 512 + kk);
        acc[mt] = __builtin_amdgcn_mfma_f32_16x16x32_bf16(af, bv, acc[mt], 0, 0, 0);
      }
    }
#pragma unroll
    for (int mt = 0; mt < 4; mt++) {
      const int hbase = colBase + mt * 16 + (lq << 2);
      float4 fb4 = *(const float4*)(fcb + hbase);
      const int l = lc;
      float v0 = lrelu(acc[mt][0] + fb4.x);
      float v1 = lrelu(acc[mt][1] + fb4.y);
      float v2 = lrelu(acc[mt][2] + fb4.z);
      float v3 = lrelu(acc[mt][3] + fb4.w);
      u16x4 pk;
      pk.x = f2bf_rne(v0); pk.y = f2bf_rne(v1); pk.z = f2bf_rne(v2); pk.w = f2bf_rne(v3);
      *(u16x4*)(xh + l * XH_STRIDE + hbase) = pk;
      float4 fv; fv.x = v0; fv.y = v1; fv.z = v2; fv.w = v3;
      *(float4*)(xh_ws + (b0 + l) * 512 + hbase) = fv;
    }
  }
  __syncthreads();

  // ---- phase B: query = xh @ q_w^T + q_b (A=xh rows l from LDS) ----
  {
    f32x4_t acc[4] = {fzero, fzero, fzero, fzero};
    for (int k0 = 0; k0 < 512; k0 += 32) {
      const int kk = k0 + kko;
      bf16x8_t af = *(const bf16x8_t*)(xh + lc * XH_STRIDE + kk);
#pragma unroll
      for (int nt = 0; nt < 4; nt++) {
        bf16x8_t bq = *(const bf16x8_t*)(qw_bf + (colBase + nt * 16 + lc) * 512 + kk);
        acc[nt] = __builtin_amdgcn_mfma_f32_16x16x32_bf16(af, bq, acc[nt], 0, 0, 0);
      }
    }
#pragma unroll
    for (int nt = 0; nt < 4; nt++) {
      const int col = colBase + nt * 16 + lc;
      const float qbias = qb[col];
#pragma unroll
      for (int r = 0; r < 4; r++)
        q_ws[(b0 + (lq << 2) + r) * 512 + col] = acc[nt][r] + qbias;
    }
  }
}

// ---------------- K2: fused yh-GEMM -> joint vec/key GEMM -> softmax/out -------
// One block per b. 8 waves; wave owns 64 h-columns x 128 l-rows.
// Phase 1 stages y k-slices into double-buffered swizzled LDS (y read ONCE per
// block instead of once per wave); both k-loops register-prefetch one iter ahead.
#define YH_STRIDE 520
#define YST_OFF_U16 (128 * YH_STRIDE)     // staging region starts here (byte 133120)
__global__ __launch_bounds__(512, 2) void attn_main(
    const float* __restrict__ y, const u16* __restrict__ fcw_bf,
    const u16* __restrict__ kw_bf, const u16* __restrict__ vw_bf,
    const float* __restrict__ fcb, const float* __restrict__ kb,
    const float* __restrict__ vb, const float* __restrict__ xh_ws,
    const float* __restrict__ q_ws, float* __restrict__ out) {
  extern __shared__ u16 smem[];
  u16* yh = smem;                             // [128][YH_STRIDE] bf16
  char* ystage = (char*)(smem + YST_OFF_U16); // 2 x 8192 B double buffer
  const int b = blockIdx.x;
  const int tid = threadIdx.x;
  const int w = tid >> 6;
  const int lane = tid & 63;
  const int lc = lane & 15;
  const int lq = lane >> 4;
  const int colBase = w << 6;
  const int kko = lq << 3;
  const f32x4_t fzero = {0.f, 0.f, 0.f, 0.f};

  const float* yb = y + (size_t)b * (128 * 512);
  // cooperative staging: thread t loads 8 fp32 of y row (t>>2), cols (t&3)*8..+7
  const int srow = tid >> 2, sq4 = tid & 3;
  const float* sgp = yb + srow * 512 + sq4 * 8;
  // XOR-swizzle bits [5:4] with (row>>1)&3: write side offset (bits4:5 == sq4, no carry)
  const int wr_off = (srow * 64 + sq4 * 16) ^ (((srow >> 1) & 3) << 4);
  const int rd_swz = ((lc >> 1) & 3) << 4;   // read row = nt*16+lc; (row>>1)&3 == (lc>>1)&3

  // ===== phase 1: yh[l][h] = lrelu(y_b @ fc_w^T + fc_b), y staged via LDS =====
  {
    f32x4_t acc[4][8];
#pragma unroll
    for (int mt = 0; mt < 4; mt++)
#pragma unroll
      for (int nt = 0; nt < 8; nt++) acc[mt][nt] = fzero;

    {  // prologue: stage slice k0=0
      float4 s0 = *(const float4*)(sgp);
      float4 s1 = *(const float4*)(sgp + 4);
      *(u16x8*)(ystage + wr_off) = cvt8pk(s0, s1);
    }
    bf16x8_t af[4];
#pragma unroll
    for (int mt = 0; mt < 4; mt++)
      af[mt] = *(const bf16x8_t*)(fcw_bf + (colBase + mt * 16 + lc) * 512 + kko);
    __syncthreads();

    int cur = 0;
    for (int k0 = 0; k0 < 512; k0 += 32) {
      const bool hasNext = (k0 + 32) < 512;
      // prefetch next y slice into regs (latency hidden under MFMAs below)
      float4 n0, n1;
      if (hasNext) {
        n0 = *(const float4*)(sgp + k0 + 32);
        n1 = *(const float4*)(sgp + k0 + 36);
      }
      // prefetch next-iter weight frags
      bf16x8_t afn[4];
      {
        const int kk2 = (hasNext ? k0 + 32 : 0) + kko;
#pragma unroll
        for (int mt = 0; mt < 4; mt++)
          afn[mt] = *(const bf16x8_t*)(fcw_bf + (colBase + mt * 16 + lc) * 512 + kk2);
      }
      // all 8 B-frags from staged LDS (conflict-free via swizzle), then 32 MFMAs
      bf16x8_t bv[8];
      const char* rbase = ystage + cur * 8192;
#pragma unroll
      for (int nt = 0; nt < 8; nt++)
        bv[nt] = *(const bf16x8_t*)(rbase + (((nt * 16 + lc) * 64 + lq * 16) ^ rd_swz));
#pragma unroll
      for (int nt = 0; nt < 8; nt++)
#pragma unroll
        for (int mt = 0; mt < 4; mt++)
          acc[mt][nt] = __builtin_amdgcn_mfma_f32_16x16x32_bf16(af[mt], bv[nt], acc[mt][nt], 0, 0, 0);
#pragma unroll
      for (int mt = 0; mt < 4; mt++) af[mt] = afn[mt];
      if (hasNext)
        *(u16x8*)(ystage + ((cur ^ 1) * 8192) + wr_off) = cvt8pk(n0, n1);
      __syncthreads();   // writers done before next iter's readers; readers of
                         // buf[cur^1] finished last iter (barrier-separated)
      cur ^= 1;
    }

    // epilogue: bias + lrelu -> yh LDS
#pragma unroll
    for (int mt = 0; mt < 4; mt++) {
      const int hbase = colBase + mt * 16 + (lq << 2);
      float4 fb4 = *(const float4*)(fcb + hbase);
#pragma unroll
      for (int nt = 0; nt < 8; nt++) {
        const int l = nt * 16 + lc;
        u16x4 pk;
        pk.x = f2bf_rne(lrelu(acc[mt][nt][0] + fb4.x));
        pk.y = f2bf_rne(lrelu(acc[mt][nt][1] + fb4.y));
        pk.z = f2bf_rne(lrelu(acc[mt][nt][2] + fb4.z));
        pk.w = f2bf_rne(lrelu(acc[mt][nt][3] + fb4.w));
        *(u16x4*)(yh + l * YH_STRIDE + hbase) = pk;
      }
    }
  }
  __syncthreads();

  // ===== phase 2: vec & key GEMMs fused, weight prefetch 1 iter ahead =====
  for (int half = 0; half < 2; half++) {
    const int c0 = colBase + half * 32 + lc;
    const int c1 = c0 + 16;
    f32x4_t av[8][2], ak[8][2];
#pragma unroll
    for (int mt = 0; mt < 8; mt++) {
      av[mt][0] = fzero; av[mt][1] = fzero;
      ak[mt][0] = fzero; ak[mt][1] = fzero;
    }

    const u16* vw0 = vw_bf + c0 * 512;
    const u16* vw1 = vw_bf + c1 * 512;
    const u16* kw0 = kw_bf + c0 * 512;
    const u16* kw1 = kw_bf + c1 * 512;
    bf16x8_t wv0 = *(const bf16x8_t*)(vw0 + kko);
    bf16x8_t wv1 = *(const bf16x8_t*)(vw1 + kko);
    bf16x8_t wk0 = *(const bf16x8_t*)(kw0 + kko);
    bf16x8_t wk1 = *(const bf16x8_t*)(kw1 + kko);

    for (int k0 = 0; k0 < 512; k0 += 32) {
      const int kk2 = ((k0 + 32) < 512 ? k0 + 32 : 0) + kko;
      bf16x8_t nv0 = *(const bf16x8_t*)(vw0 + kk2);
      bf16x8_t nv1 = *(const bf16x8_t*)(vw1 + kk2);
      bf16x8_t nk0 = *(const bf16x8_t*)(kw0 + kk2);
      bf16x8_t nk1 = *(const bf16x8_t*)(kw1 + kk2);
      const int kk = k0 + kko;
      bf16x8_t af[8];
#pragma unroll
      for (int mt = 0; mt < 8; mt++)
        af[mt] = *(const bf16x8_t*)(yh + (mt * 16 + lc) * YH_STRIDE + kk);
      __builtin_amdgcn_s_setprio(1);
#pragma unroll
      for (int mt = 0; mt < 8; mt++) {
        av[mt][0] = __builtin_amdgcn_mfma_f32_16x16x32_bf16(af[mt], wv0, av[mt][0], 0, 0, 0);
        av[mt][1] = __builtin_amdgcn_mfma_f32_16x16x32_bf16(af[mt], wv1, av[mt][1], 0, 0, 0);
        ak[mt][0] = __builtin_amdgcn_mfma_f32_16x16x32_bf16(af[mt], wk0, ak[mt][0], 0, 0, 0);
        ak[mt][1] = __builtin_amdgcn_mfma_f32_16x16x32_bf16(af[mt], wk1, ak[mt][1], 0, 0, 0);
      }
      __builtin_amdgcn_s_setprio(0);
      wv0 = nv0; wv1 = nv1; wk0 = nk0; wk1 = nk1;
    }

#pragma unroll
    for (int nt = 0; nt < 2; nt++) {
      const int c = (nt == 0) ? c0 : c1;
      const float kbias = kb[c];
      const float vbias = vb[c];
      const float qv = q_ws[(size_t)b * 512 + c];
      float mx = -1e30f;
#pragma unroll
      for (int mt = 0; mt < 8; mt++)
#pragma unroll
        for (int r = 0; r < 4; r++) {
          float t = (ak[mt][nt][r] + kbias) * qv;
          ak[mt][nt][r] = t;
          mx = fmaxf(mx, t);
        }
      mx = fmaxf(mx, __shfl_xor(mx, 16));
      mx = fmaxf(mx, __shfl_xor(mx, 32));
      float s = 0.f, hp = 0.f;
#pragma unroll
      for (int mt = 0; mt < 8; mt++)
#pragma unroll
        for (int r = 0; r < 4; r++) {
          float p = __expf(ak[mt][nt][r] - mx);
          float vv = lrelu(av[mt][nt][r] + vbias);   // lrelu pos-homogeneous: e*lrelu(vec)
          s += p;
          hp = fmaf(p, vv, hp);
        }
      s += __shfl_xor(s, 16);   s += __shfl_xor(s, 32);
      hp += __shfl_xor(hp, 16); hp += __shfl_xor(hp, 32);
      if (lq == 0)
        out[(size_t)b * 512 + c] = (xh_ws[(size_t)b * 512 + c] + hp / s) * 0.5f;
    }
  }
}

extern "C" void kernel_launch(void* const* d_in, const int* in_sizes, int n_in,
                              void* d_out, int out_size, void* d_ws, size_t ws_size,
                              hipStream_t stream) {
  const float* x   = (const float*)d_in[0];
  const float* y   = (const float*)d_in[1];
  const float* fcw = (const float*)d_in[2];
  const float* fcb = (const float*)d_in[3];
  const float* qw  = (const float*)d_in[4];
  const float* qb  = (const float*)d_in[5];
  const float* kw  = (const float*)d_in[6];
  const float* kb  = (const float*)d_in[7];
  const float* vw  = (const float*)d_in[8];
  const float* vb  = (const float*)d_in[9];
  float* out = (float*)d_out;

  // ws: fcw_bf qw_bf kw_bf vw_bf (4 x 512KB u16) | xh_ws (4MB f32) | q_ws (4MB)
  u16* fcw_bf = (u16*)d_ws;
  u16* qw_bf  = fcw_bf + 262144;
  u16* kw_bf  = qw_bf + 262144;
  u16* vw_bf  = kw_bf + 262144;
  float* xh_ws = (float*)(vw_bf + 262144);
  float* q_ws  = xh_ws + (size_t)2048 * 512;

  convert_weights<<<1024, 256, 0, stream>>>(fcw, qw, kw, vw, fcw_bf);

  xh_query<<<128, 512, 0, stream>>>(x, fcw_bf, qw_bf, fcb, qb, xh_ws, q_ws);

  const size_t lds_bytes = (size_t)(128 * YH_STRIDE + 2 * 4096) * sizeof(u16);  // 149504 B
  hipFuncSetAttribute((const void*)attn_main,
                      hipFuncAttributeMaxDynamicSharedMemorySize, (int)lds_bytes);
  attn_main<<<2048, 512, lds_bytes, stream>>>(y, fcw_bf, kw_bf, vw_bf, fcb, kb, vb,
                                              xh_ws, q_ws, out);
}